// Round 1
// baseline (2947.438 us; speedup 1.0000x reference)
//
#include <hip/hip_runtime.h>
#include <math.h>

#define BATCH 4
#define SEQL 1024
#define DMODEL 256
#define DINNER 512
#define DSTATE 16
#define DTRANK 16
#define NLAYERS 4

static __device__ __forceinline__ float siluf(float x) {
    return x / (1.0f + expf(-x));
}
static __device__ __forceinline__ float softplusf(float x) {
    return (x > 0.0f) ? (x + log1pf(expf(-x))) : log1pf(expf(x));
}

// ---------------------------------------------------------------------------
// Embedding conv (k=3, SAME) + BatchNorm + SiLU  ->  h (B*L, DMODEL) row-major
// ---------------------------------------------------------------------------
__global__ void k_embed(const float* __restrict__ x, const float* __restrict__ emb_w,
                        const float* __restrict__ gamma, const float* __restrict__ beta,
                        const float* __restrict__ mean, const float* __restrict__ var,
                        float* __restrict__ h) {
    const int m = blockIdx.x;             // b*L + l
    const int d = threadIdx.x;            // 0..255
    const int b = m >> 10;
    const int l = m & 1023;
    const float xm1 = (l > 0)    ? x[b * SEQL + l - 1] : 0.0f;
    const float x0  =              x[b * SEQL + l];
    const float xp1 = (l < 1023) ? x[b * SEQL + l + 1] : 0.0f;
    float c = xm1 * emb_w[d * 3 + 0] + x0 * emb_w[d * 3 + 1] + xp1 * emb_w[d * 3 + 2];
    const float inv = 1.0f / sqrtf(var[d] + 1e-5f);
    c = (c - mean[d]) * (inv * gamma[d]) + beta[d];
    h[(size_t)m * DMODEL + d] = siluf(c);
}

// ---------------------------------------------------------------------------
// Generic fp32 tiled SGEMM, C[M,N] = A[M,K(lda)] * B[N,K(ldb)]^T  (NT)
// EPI 0: none.  EPI 1: softplus(acc + bias[n])
// ---------------------------------------------------------------------------
template <int BM, int BN, int BK, int TM, int TN, int EPI>
__global__ __launch_bounds__((BM / TM) * (BN / TN))
void sgemm_nt(const float* __restrict__ A, int lda,
              const float* __restrict__ Bw, int ldb,
              const float* __restrict__ bias,
              float* __restrict__ C, int ldc, int K) {
    constexpr int TX = BN / TN;
    constexpr int TY = BM / TM;
    constexpr int NT = TX * TY;
    static_assert(NT == 256, "expect 256 threads");
    static_assert(BK % 4 == 0, "");

    const int tid = threadIdx.x;
    const int tx = tid % TX;
    const int ty = tid / TX;
    const int m0 = blockIdx.y * BM;
    const int n0 = blockIdx.x * BN;

    __shared__ float As[BK][BM + 4];
    __shared__ float Bs[BK][BN + 4];

    float acc[TM][TN] = {};

    constexpr int AV = BM * BK / 4;  // number of float4 loads for A tile
    constexpr int BV = BN * BK / 4;

    for (int kt = 0; kt < K; kt += BK) {
        for (int v = tid; v < AV; v += NT) {
            const int i = v / (BK / 4);
            const int jv = v % (BK / 4);
            const float4 a4 = *reinterpret_cast<const float4*>(
                &A[(size_t)(m0 + i) * lda + kt + jv * 4]);
            As[jv * 4 + 0][i] = a4.x;
            As[jv * 4 + 1][i] = a4.y;
            As[jv * 4 + 2][i] = a4.z;
            As[jv * 4 + 3][i] = a4.w;
        }
        for (int v = tid; v < BV; v += NT) {
            const int i = v / (BK / 4);
            const int jv = v % (BK / 4);
            const float4 b4 = *reinterpret_cast<const float4*>(
                &Bw[(size_t)(n0 + i) * ldb + kt + jv * 4]);
            Bs[jv * 4 + 0][i] = b4.x;
            Bs[jv * 4 + 1][i] = b4.y;
            Bs[jv * 4 + 2][i] = b4.z;
            Bs[jv * 4 + 3][i] = b4.w;
        }
        __syncthreads();
#pragma unroll
        for (int k = 0; k < BK; ++k) {
            float a[TM], b[TN];
#pragma unroll
            for (int i = 0; i < TM; ++i) a[i] = As[k][ty * TM + i];
#pragma unroll
            for (int j = 0; j < TN; ++j) b[j] = Bs[k][tx * TN + j];
#pragma unroll
            for (int i = 0; i < TM; ++i)
#pragma unroll
                for (int j = 0; j < TN; ++j) acc[i][j] = fmaf(a[i], b[j], acc[i][j]);
        }
        __syncthreads();
    }

#pragma unroll
    for (int i = 0; i < TM; ++i) {
        const int m = m0 + ty * TM + i;
#pragma unroll
        for (int j = 0; j < TN; ++j) {
            const int n = n0 + tx * TN + j;
            float v = acc[i][j];
            if (EPI == 1) v = softplusf(v + bias[n]);
            C[(size_t)m * ldc + n] = v;
        }
    }
}

// ---------------------------------------------------------------------------
// Causal depthwise conv (k=4) + bias + SiLU on xi (= xz[:, 0:512]) -> xc
// ---------------------------------------------------------------------------
__global__ void k_conv(const float* __restrict__ xz, const float* __restrict__ cw,
                       const float* __restrict__ cb, float* __restrict__ xc) {
    const int m = blockIdx.x;   // b*L + l
    const int d = threadIdx.x;  // 0..511
    const int l = m & 1023;
    float acc = cb[d];
#pragma unroll
    for (int k = 0; k < 4; ++k) {
        const int ll = l - 3 + k;
        if (ll >= 0) acc = fmaf(xz[(size_t)(m - 3 + k) * (2 * DINNER) + d], cw[d * 4 + k], acc);
    }
    xc[(size_t)m * DINNER + d] = siluf(acc);
}

// ---------------------------------------------------------------------------
// Selective scan.  One block = (b, group of 16 channels); lane layout:
// thread = d_local*16 + n. h kept in register, reduce over n via shfl_xor.
// Fused epilogue: (y + u*D) * silu(z)
// ---------------------------------------------------------------------------
__global__ __launch_bounds__(256) void k_scan(
    const float* __restrict__ xc, const float* __restrict__ dt,
    const float* __restrict__ xdbl, const float* __restrict__ xz,
    const float* __restrict__ A_log, const float* __restrict__ D_skip,
    float* __restrict__ y) {
    const int b = blockIdx.y;
    const int d = blockIdx.x * 16 + (threadIdx.x >> 4);
    const int n = threadIdx.x & 15;

    const float a = -expf(A_log[d * DSTATE + n]);
    const float Dsk = D_skip[d];

    float h = 0.0f;
    const size_t mbase = (size_t)b * SEQL;

    // prefetch t=0
    size_t m = mbase;
    float dtv = dt[m * DINNER + d];
    float uv = xc[m * DINNER + d];
    float Bv = xdbl[m * 48 + DTRANK + n];
    float Cv = xdbl[m * 48 + DTRANK + DSTATE + n];

    for (int t = 0; t < SEQL; ++t) {
        const size_t mc = mbase + t;
        float ndt = 0.f, nu = 0.f, nB = 0.f, nC = 0.f;
        if (t + 1 < SEQL) {
            const size_t mn = mc + 1;
            ndt = dt[mn * DINNER + d];
            nu = xc[mn * DINNER + d];
            nB = xdbl[mn * 48 + DTRANK + n];
            nC = xdbl[mn * 48 + DTRANK + DSTATE + n];
        }
        h = expf(dtv * a) * h + dtv * Bv * uv;
        float p = h * Cv;
        p += __shfl_xor(p, 1);
        p += __shfl_xor(p, 2);
        p += __shfl_xor(p, 4);
        p += __shfl_xor(p, 8);
        if (n == 0) {
            const float zv = xz[mc * (2 * DINNER) + DINNER + d];
            y[mc * DINNER + d] = (p + uv * Dsk) * siluf(zv);
        }
        dtv = ndt; uv = nu; Bv = nB; Cv = nC;
    }
}

// ---------------------------------------------------------------------------
// Column sums of last layer's out_proj_w: wsum[d] = sum_o w[o,d]
// ---------------------------------------------------------------------------
__global__ void k_wsum(const float* __restrict__ w, float* __restrict__ wsum) {
    const int d = threadIdx.x;  // 0..511
    float s = 0.0f;
    for (int o = 0; o < DMODEL; ++o) s += w[(size_t)o * DINNER + d];
    wsum[d] = s;
}

// ---------------------------------------------------------------------------
// Final: out[m] = dot(y[m, :512], wsum)   (one wave per row)
// ---------------------------------------------------------------------------
__global__ __launch_bounds__(64) void k_final(const float* __restrict__ y,
                                              const float* __restrict__ wsum,
                                              float* __restrict__ out) {
    const int m = blockIdx.x;
    const int lane = threadIdx.x;
    float r = 0.0f;
#pragma unroll
    for (int k = 0; k < DINNER / 64; ++k)
        r = fmaf(y[(size_t)m * DINNER + lane + k * 64], wsum[lane + k * 64], r);
#pragma unroll
    for (int off = 32; off > 0; off >>= 1) r += __shfl_xor(r, off);
    if (lane == 0) out[m] = r;
}

// ---------------------------------------------------------------------------
extern "C" void kernel_launch(void* const* d_in, const int* in_sizes, int n_in,
                              void* d_out, int out_size, void* d_ws, size_t ws_size,
                              hipStream_t stream) {
    const float* x        = (const float*)d_in[0];
    const float* emb_w    = (const float*)d_in[2];
    const float* bn_gamma = (const float*)d_in[3];
    const float* bn_beta  = (const float*)d_in[4];
    const float* bn_mean  = (const float*)d_in[5];
    const float* bn_var   = (const float*)d_in[6];
    const float* in_proj_w  = (const float*)d_in[7];
    const float* conv_w     = (const float*)d_in[8];
    const float* conv_b     = (const float*)d_in[9];
    const float* x_proj_w   = (const float*)d_in[10];
    const float* dt_proj_w  = (const float*)d_in[11];
    const float* dt_proj_b  = (const float*)d_in[12];
    const float* A_log      = (const float*)d_in[13];
    const float* D_skip     = (const float*)d_in[14];
    const float* out_proj_w = (const float*)d_in[15];
    float* out = (float*)d_out;
    float* ws = (float*)d_ws;

    const int M = BATCH * SEQL;  // 4096

    // workspace layout (floats)
    float* h    = ws;                        // 4096*256   = 1,048,576
    float* xz   = h + (size_t)M * DMODEL;    // 4096*1024  = 4,194,304
    float* xc   = xz + (size_t)M * 2 * DINNER;  // 4096*512
    float* xdbl = xc + (size_t)M * DINNER;   // 4096*48
    float* dt   = xdbl + (size_t)M * 48;     // 4096*512
    float* y    = dt + (size_t)M * DINNER;   // 4096*512
    float* wsum = y + (size_t)M * DINNER;    // 512

    k_embed<<<M, DMODEL, 0, stream>>>(x, emb_w, bn_gamma, bn_beta, bn_mean, bn_var, h);

    for (int i = 0; i < NLAYERS; ++i) {
        const float* in_w  = in_proj_w + (size_t)i * 2 * DINNER * DMODEL;
        const float* cw    = conv_w + (size_t)i * DINNER * 4;
        const float* cb    = conv_b + (size_t)i * DINNER;
        const float* xp_w  = x_proj_w + (size_t)i * 48 * DINNER;
        const float* dtp_w = dt_proj_w + (size_t)i * DINNER * DTRANK;
        const float* dtp_b = dt_proj_b + (size_t)i * DINNER;
        const float* Al    = A_log + (size_t)i * DINNER * DSTATE;
        const float* Dsk   = D_skip + (size_t)i * DINNER;
        const float* o_w   = out_proj_w + (size_t)i * DMODEL * DINNER;

        // xz[M,1024] = h[M,256] @ in_w[1024,256]^T
        sgemm_nt<128, 64, 16, 8, 4, 0><<<dim3(1024 / 64, M / 128), 256, 0, stream>>>(
            h, DMODEL, in_w, DMODEL, nullptr, xz, 2 * DINNER, DMODEL);

        // depthwise causal conv + silu -> xc[M,512]
        k_conv<<<M, DINNER, 0, stream>>>(xz, cw, cb, xc);

        // xdbl[M,48] = xc[M,512] @ xp_w[48,512]^T
        sgemm_nt<32, 48, 16, 2, 3, 0><<<dim3(1, M / 32), 256, 0, stream>>>(
            xc, DINNER, xp_w, DINNER, nullptr, xdbl, 48, DINNER);

        // dt[M,512] = softplus(xdbl[:, :16] @ dtp_w[512,16]^T + dtp_b)
        sgemm_nt<64, 64, 16, 4, 4, 1><<<dim3(DINNER / 64, M / 64), 256, 0, stream>>>(
            xdbl, 48, dtp_w, DTRANK, dtp_b, dt, DINNER, DTRANK);

        // selective scan (+u*D, *silu(z)) -> y[M,512]
        k_scan<<<dim3(DINNER / 16, BATCH), 256, 0, stream>>>(xc, dt, xdbl, xz, Al, Dsk, y);

        if (i < NLAYERS - 1) {
            // h[M,256] = y[M,512] @ o_w[256,512]^T
            sgemm_nt<64, 64, 16, 4, 4, 0><<<dim3(DMODEL / 64, M / 64), 256, 0, stream>>>(
                y, DINNER, o_w, DINNER, nullptr, h, DMODEL, DINNER);
        } else {
            k_wsum<<<1, DINNER, 0, stream>>>(o_w, wsum);
            k_final<<<M, 64, 0, stream>>>(y, wsum, out);
        }
    }
}

// Round 2
// 874.129 us; speedup vs baseline: 3.3719x; 3.3719x over previous
//
#include <hip/hip_runtime.h>
#include <math.h>

#define BATCH 4
#define SEQL 1024
#define DMODEL 256
#define DINNER 512
#define DSTATE 16
#define DTRANK 16
#define NLAYERS 4

static __device__ __forceinline__ float siluf(float x) {
    return x / (1.0f + expf(-x));
}
static __device__ __forceinline__ float softplusf(float x) {
    return (x > 0.0f) ? (x + log1pf(expf(-x))) : log1pf(expf(x));
}

// ---------------------------------------------------------------------------
// Embedding conv (k=3, SAME) + BatchNorm + SiLU  ->  h (B*L, DMODEL) row-major
// ---------------------------------------------------------------------------
__global__ void k_embed(const float* __restrict__ x, const float* __restrict__ emb_w,
                        const float* __restrict__ gamma, const float* __restrict__ beta,
                        const float* __restrict__ mean, const float* __restrict__ var,
                        float* __restrict__ h) {
    const int m = blockIdx.x;             // b*L + l
    const int d = threadIdx.x;            // 0..255
    const int b = m >> 10;
    const int l = m & 1023;
    const float xm1 = (l > 0)    ? x[b * SEQL + l - 1] : 0.0f;
    const float x0  =              x[b * SEQL + l];
    const float xp1 = (l < 1023) ? x[b * SEQL + l + 1] : 0.0f;
    float c = xm1 * emb_w[d * 3 + 0] + x0 * emb_w[d * 3 + 1] + xp1 * emb_w[d * 3 + 2];
    const float inv = 1.0f / sqrtf(var[d] + 1e-5f);
    c = (c - mean[d]) * (inv * gamma[d]) + beta[d];
    h[(size_t)m * DMODEL + d] = siluf(c);
}

// ---------------------------------------------------------------------------
// Generic fp32 tiled SGEMM, C[M,N] = A[M,K(lda)] * B[N,K(ldb)]^T  (NT)
// EPI 0: none.  EPI 1: softplus(acc + bias[n])
// ---------------------------------------------------------------------------
template <int BM, int BN, int BK, int TM, int TN, int EPI>
__global__ __launch_bounds__((BM / TM) * (BN / TN))
void sgemm_nt(const float* __restrict__ A, int lda,
              const float* __restrict__ Bw, int ldb,
              const float* __restrict__ bias,
              float* __restrict__ C, int ldc, int K) {
    constexpr int TX = BN / TN;
    constexpr int TY = BM / TM;
    constexpr int NT = TX * TY;
    static_assert(NT == 256, "expect 256 threads");
    static_assert(BK % 4 == 0, "");

    const int tid = threadIdx.x;
    const int tx = tid % TX;
    const int ty = tid / TX;
    const int m0 = blockIdx.y * BM;
    const int n0 = blockIdx.x * BN;

    __shared__ float As[BK][BM + 4];
    __shared__ float Bs[BK][BN + 4];

    float acc[TM][TN] = {};

    constexpr int AV = BM * BK / 4;  // number of float4 loads for A tile
    constexpr int BV = BN * BK / 4;

    for (int kt = 0; kt < K; kt += BK) {
        for (int v = tid; v < AV; v += NT) {
            const int i = v / (BK / 4);
            const int jv = v % (BK / 4);
            const float4 a4 = *reinterpret_cast<const float4*>(
                &A[(size_t)(m0 + i) * lda + kt + jv * 4]);
            As[jv * 4 + 0][i] = a4.x;
            As[jv * 4 + 1][i] = a4.y;
            As[jv * 4 + 2][i] = a4.z;
            As[jv * 4 + 3][i] = a4.w;
        }
        for (int v = tid; v < BV; v += NT) {
            const int i = v / (BK / 4);
            const int jv = v % (BK / 4);
            const float4 b4 = *reinterpret_cast<const float4*>(
                &Bw[(size_t)(n0 + i) * ldb + kt + jv * 4]);
            Bs[jv * 4 + 0][i] = b4.x;
            Bs[jv * 4 + 1][i] = b4.y;
            Bs[jv * 4 + 2][i] = b4.z;
            Bs[jv * 4 + 3][i] = b4.w;
        }
        __syncthreads();
#pragma unroll
        for (int k = 0; k < BK; ++k) {
            float a[TM], b[TN];
#pragma unroll
            for (int i = 0; i < TM; ++i) a[i] = As[k][ty * TM + i];
#pragma unroll
            for (int j = 0; j < TN; ++j) b[j] = Bs[k][tx * TN + j];
#pragma unroll
            for (int i = 0; i < TM; ++i)
#pragma unroll
                for (int j = 0; j < TN; ++j) acc[i][j] = fmaf(a[i], b[j], acc[i][j]);
        }
        __syncthreads();
    }

#pragma unroll
    for (int i = 0; i < TM; ++i) {
        const int m = m0 + ty * TM + i;
#pragma unroll
        for (int j = 0; j < TN; ++j) {
            const int n = n0 + tx * TN + j;
            float v = acc[i][j];
            if (EPI == 1) v = softplusf(v + bias[n]);
            C[(size_t)m * ldc + n] = v;
        }
    }
}

// ---------------------------------------------------------------------------
// Causal depthwise conv (k=4) + bias + SiLU on xi (= xz[:, 0:512]) -> xc
// ---------------------------------------------------------------------------
__global__ void k_conv(const float* __restrict__ xz, const float* __restrict__ cw,
                       const float* __restrict__ cb, float* __restrict__ xc) {
    const int m = blockIdx.x;   // b*L + l
    const int d = threadIdx.x;  // 0..511
    const int l = m & 1023;
    float acc = cb[d];
#pragma unroll
    for (int k = 0; k < 4; ++k) {
        const int ll = l - 3 + k;
        if (ll >= 0) acc = fmaf(xz[(size_t)(m - 3 + k) * (2 * DINNER) + d], cw[d * 4 + k], acc);
    }
    xc[(size_t)m * DINNER + d] = siluf(acc);
}

// ---------------------------------------------------------------------------
// Chunked parallel selective scan.
// One block per (b, d): 256 threads = (chunk c: 16) x (state n: 16).
// Pass A: per-chunk affine summary (P = prod dA, S = end state from h=0).
// Combine: exclusive affine prefix over chunks via LDS.
// Pass B: replay chunk from correct h_init; fused (y + u*D) * silu(z).
// ---------------------------------------------------------------------------
__global__ __launch_bounds__(256) void k_scan2(
    const float* __restrict__ xc, const float* __restrict__ dt,
    const float* __restrict__ xdbl, const float* __restrict__ xz,
    const float* __restrict__ A_log, const float* __restrict__ D_skip,
    float* __restrict__ y) {
    const int d = blockIdx.x;   // 0..511
    const int b = blockIdx.y;   // 0..3
    const int tid = threadIdx.x;
    const int c = tid >> 4;     // chunk 0..15
    const int n = tid & 15;     // state  0..15

    __shared__ float dt_s[SEQL];
    __shared__ float u_s[SEQL];
    __shared__ float PS[16][16][2];  // [c][n][{P,S}]

    const size_t mbase = (size_t)b * SEQL;

    // cooperative stage of the d-column of dt and u
    for (int t = tid; t < SEQL; t += 256) {
        dt_s[t] = dt[(mbase + t) * DINNER + d];
        u_s[t]  = xc[(mbase + t) * DINNER + d];
    }
    __syncthreads();

    const float a = -expf(A_log[d * DSTATE + n]);
    const int t0 = c * 64;

    // ---- Pass A: chunk summary ----
    float P = 1.0f, S = 0.0f;
    float Bv = xdbl[(mbase + t0) * 48 + DTRANK + n];
    for (int t = t0; t < t0 + 64; ++t) {
        float Bn = (t + 1 < t0 + 64) ? xdbl[(mbase + t + 1) * 48 + DTRANK + n] : 0.0f;
        const float dtv = dt_s[t];
        const float e = expf(dtv * a);
        P *= e;
        S = fmaf(e, S, dtv * Bv * u_s[t]);
        Bv = Bn;
    }
    PS[c][n][0] = P;
    PS[c][n][1] = S;
    __syncthreads();

    // ---- exclusive affine prefix: initial state for chunk c ----
    float h = 0.0f;
    for (int j = 0; j < c; ++j) h = fmaf(PS[j][n][0], h, PS[j][n][1]);

    // ---- Pass B: replay with correct init, fused epilogue ----
    const float Dsk = D_skip[d];
    float Bv2 = xdbl[(mbase + t0) * 48 + DTRANK + n];
    float Cv  = xdbl[(mbase + t0) * 48 + DTRANK + DSTATE + n];
    for (int t = t0; t < t0 + 64; ++t) {
        float Bn = 0.0f, Cn = 0.0f;
        if (t + 1 < t0 + 64) {
            Bn = xdbl[(mbase + t + 1) * 48 + DTRANK + n];
            Cn = xdbl[(mbase + t + 1) * 48 + DTRANK + DSTATE + n];
        }
        const float dtv = dt_s[t];
        const float uv  = u_s[t];
        const float e = expf(dtv * a);
        h = fmaf(e, h, dtv * Bv2 * uv);
        float p = h * Cv;
        p += __shfl_xor(p, 1);
        p += __shfl_xor(p, 2);
        p += __shfl_xor(p, 4);
        p += __shfl_xor(p, 8);
        if (n == 0) {
            const float zv = xz[(mbase + t) * (2 * DINNER) + DINNER + d];
            y[(mbase + t) * DINNER + d] = (p + uv * Dsk) * siluf(zv);
        }
        Bv2 = Bn;
        Cv = Cn;
    }
}

// ---------------------------------------------------------------------------
// Column sums of last layer's out_proj_w: wsum[d] = sum_o w[o,d]
// ---------------------------------------------------------------------------
__global__ void k_wsum(const float* __restrict__ w, float* __restrict__ wsum) {
    const int d = threadIdx.x;  // 0..511
    float s = 0.0f;
    for (int o = 0; o < DMODEL; ++o) s += w[(size_t)o * DINNER + d];
    wsum[d] = s;
}

// ---------------------------------------------------------------------------
// Final: out[m] = dot(y[m, :512], wsum)   (one wave per row)
// ---------------------------------------------------------------------------
__global__ __launch_bounds__(64) void k_final(const float* __restrict__ y,
                                              const float* __restrict__ wsum,
                                              float* __restrict__ out) {
    const int m = blockIdx.x;
    const int lane = threadIdx.x;
    float r = 0.0f;
#pragma unroll
    for (int k = 0; k < DINNER / 64; ++k)
        r = fmaf(y[(size_t)m * DINNER + lane + k * 64], wsum[lane + k * 64], r);
#pragma unroll
    for (int off = 32; off > 0; off >>= 1) r += __shfl_xor(r, off);
    if (lane == 0) out[m] = r;
}

// ---------------------------------------------------------------------------
extern "C" void kernel_launch(void* const* d_in, const int* in_sizes, int n_in,
                              void* d_out, int out_size, void* d_ws, size_t ws_size,
                              hipStream_t stream) {
    const float* x        = (const float*)d_in[0];
    const float* emb_w    = (const float*)d_in[2];
    const float* bn_gamma = (const float*)d_in[3];
    const float* bn_beta  = (const float*)d_in[4];
    const float* bn_mean  = (const float*)d_in[5];
    const float* bn_var   = (const float*)d_in[6];
    const float* in_proj_w  = (const float*)d_in[7];
    const float* conv_w     = (const float*)d_in[8];
    const float* conv_b     = (const float*)d_in[9];
    const float* x_proj_w   = (const float*)d_in[10];
    const float* dt_proj_w  = (const float*)d_in[11];
    const float* dt_proj_b  = (const float*)d_in[12];
    const float* A_log      = (const float*)d_in[13];
    const float* D_skip     = (const float*)d_in[14];
    const float* out_proj_w = (const float*)d_in[15];
    float* out = (float*)d_out;
    float* ws = (float*)d_ws;

    const int M = BATCH * SEQL;  // 4096

    // workspace layout (floats)
    float* h    = ws;                        // 4096*256
    float* xz   = h + (size_t)M * DMODEL;    // 4096*1024
    float* xc   = xz + (size_t)M * 2 * DINNER;  // 4096*512
    float* xdbl = xc + (size_t)M * DINNER;   // 4096*48
    float* dt   = xdbl + (size_t)M * 48;     // 4096*512
    float* y    = dt + (size_t)M * DINNER;   // 4096*512
    float* wsum = y + (size_t)M * DINNER;    // 512

    k_embed<<<M, DMODEL, 0, stream>>>(x, emb_w, bn_gamma, bn_beta, bn_mean, bn_var, h);

    for (int i = 0; i < NLAYERS; ++i) {
        const float* in_w  = in_proj_w + (size_t)i * 2 * DINNER * DMODEL;
        const float* cw    = conv_w + (size_t)i * DINNER * 4;
        const float* cb    = conv_b + (size_t)i * DINNER;
        const float* xp_w  = x_proj_w + (size_t)i * 48 * DINNER;
        const float* dtp_w = dt_proj_w + (size_t)i * DINNER * DTRANK;
        const float* dtp_b = dt_proj_b + (size_t)i * DINNER;
        const float* Al    = A_log + (size_t)i * DINNER * DSTATE;
        const float* Dsk   = D_skip + (size_t)i * DINNER;
        const float* o_w   = out_proj_w + (size_t)i * DMODEL * DINNER;

        // xz[M,1024] = h[M,256] @ in_w[1024,256]^T
        sgemm_nt<128, 64, 16, 8, 4, 0><<<dim3(1024 / 64, M / 128), 256, 0, stream>>>(
            h, DMODEL, in_w, DMODEL, nullptr, xz, 2 * DINNER, DMODEL);

        // depthwise causal conv + silu -> xc[M,512]
        k_conv<<<M, DINNER, 0, stream>>>(xz, cw, cb, xc);

        // xdbl[M,48] = xc[M,512] @ xp_w[48,512]^T
        sgemm_nt<32, 48, 16, 2, 3, 0><<<dim3(1, M / 32), 256, 0, stream>>>(
            xc, DINNER, xp_w, DINNER, nullptr, xdbl, 48, DINNER);

        // dt[M,512] = softplus(xdbl[:, :16] @ dtp_w[512,16]^T + dtp_b)
        sgemm_nt<64, 64, 16, 4, 4, 1><<<dim3(DINNER / 64, M / 64), 256, 0, stream>>>(
            xdbl, 48, dtp_w, DTRANK, dtp_b, dt, DINNER, DTRANK);

        // chunked parallel scan (+u*D, *silu(z)) -> y[M,512]
        k_scan2<<<dim3(DINNER, BATCH), 256, 0, stream>>>(xc, dt, xdbl, xz, Al, Dsk, y);

        if (i < NLAYERS - 1) {
            // h[M,256] = y[M,512] @ o_w[256,512]^T
            sgemm_nt<64, 64, 16, 4, 4, 0><<<dim3(DMODEL / 64, M / 64), 256, 0, stream>>>(
                y, DINNER, o_w, DINNER, nullptr, h, DMODEL, DINNER);
        } else {
            k_wsum<<<1, DINNER, 0, stream>>>(o_w, wsum);
            k_final<<<M, 64, 0, stream>>>(y, wsum, out);
        }
    }
}